// Round 1
// baseline (1191.875 us; speedup 1.0000x reference)
//
#include <hip/hip_runtime.h>
#include <cstdint>
#include <cstddef>

#define T_STEPS 1024
#define BATCH   512
#define HID     64
#define G4      256
#define IN      32

typedef __attribute__((ext_vector_type(2))) _Float16 half2_t;

static __device__ __forceinline__ half2_t f_as_h2(float f) {
  union { float f; half2_t h; } u; u.f = f; return u.h;
}

static __device__ __forceinline__ float dot2(half2_t a, half2_t b, float c) {
#if defined(__has_builtin)
#if __has_builtin(__builtin_amdgcn_fdot2)
  return __builtin_amdgcn_fdot2(a, b, c, false);
#else
  return c + (float)a[0]*(float)b[0] + (float)a[1]*(float)b[1];
#endif
#else
  return c + (float)a[0]*(float)b[0] + (float)a[1]*(float)b[1];
#endif
}

static __device__ __forceinline__ float sigm(float x) {
  return __builtin_amdgcn_rcpf(1.0f + __expf(-x));
}
static __device__ __forceinline__ float tanh_(float x) {
  // 1 - 2/(exp(2x)+1); saturates correctly at +/-inf
  return 1.0f - 2.0f * __builtin_amdgcn_rcpf(__expf(2.0f * x) + 1.0f);
}

// Block = 256 threads, 1 batch element per block, grid = 512 blocks (2/CU).
// Threads   0.. 95 : L1 matmul tiles  (kc = t>>5 in 0..2, rgrp = t&31, 8 rows x 32 k)
// Threads  96..223 : L2 matmul tiles  (u = t-96, kc = u>>5 in 0..3, rgrp = u&31)
// Threads 224..255 : x prefetch lanes (i = t-224)
// Owners: t<64 -> layer-1 unit t (holds c1 in reg); 64<=t<128 -> layer-2 unit t-64 (c2).
__global__ __launch_bounds__(256, 2) void lstm_fused(
    const float* __restrict__ x,
    const float* __restrict__ w_ih1, const float* __restrict__ w_hh1,
    const float* __restrict__ b_ih1, const float* __restrict__ b_hh1,
    const float* __restrict__ w_ih2, const float* __restrict__ w_hh2,
    const float* __restrict__ b_ih2, const float* __restrict__ b_hh2,
    const float* __restrict__ fc1_w, const float* __restrict__ fc1_b,
    const float* __restrict__ fc2_w, const float* __restrict__ fc2_b,
    const float* __restrict__ ln_g, const float* __restrict__ ln_b,
    float* __restrict__ out)
{
  __shared__ __align__(16) _Float16 h1h[64];     // h1_{t}   (f16)
  __shared__ __align__(16) _Float16 h2h[64];     // h2_{t-1} (f16)
  __shared__ __align__(16) _Float16 xh[2][32];   // x_t staging, double-buffered
  __shared__ __align__(16) float pt1[3][256];    // L1 k-chunk partial sums
  __shared__ __align__(16) float pt2[4][256];    // L2 k-chunk partial sums
  __shared__ float bsum1[256], bsum2[256];       // b_ih + b_hh
  __shared__ __align__(16) float hfin[64];       // final h2 in f32
  __shared__ __align__(16) float y1s[128];
  __shared__ __align__(16) float y2s[128];
  __shared__ float redmu, redrs;

  const int t = threadIdx.x;
  const int b = blockIdx.x;

  // ---- init LDS state ----
  if (t < 64)        h1h[t]      = (_Float16)0.0f;
  else if (t < 128)  h2h[t - 64] = (_Float16)0.0f;
  bsum1[t] = b_ih1[t] + b_hh1[t];
  bsum2[t] = b_ih2[t] + b_hh2[t];
  if (t >= 224) {
    int i = t - 224;
    xh[0][i] = (_Float16)x[(size_t)b * (T_STEPS * IN) + i];  // x_0
    xh[1][i] = (_Float16)0.0f;
  }

  // ---- load stationary weights into registers (f16 pairs, 8 rows x 32 k) ----
  half2_t wr[8][16];
  const bool isMM = (t < 224);
  const bool isL1 = (t < 96);
  const int  u    = isL1 ? t : (t - 96);
  const int  kc   = u >> 5;
  const int  rg   = u & 31;
  if (isMM) {
    #pragma unroll
    for (int r = 0; r < 8; ++r) {
      const int g = rg * 8 + r;
      const float* src;
      if (isL1) {
        // L1 row g: K = [x(32) | h1(64)] -> kc0: w_ih1[g,0:32]; kc1/2: w_hh1[g, 32*(kc-1) : ...]
        src = (kc == 0) ? (w_ih1 + g * 32) : (w_hh1 + g * 64 + (kc - 1) * 32);
      } else {
        // L2 row g: K = [h1(64) | h2(64)] -> kc0/1: w_ih2; kc2/3: w_hh2
        src = (kc < 2) ? (w_ih2 + g * 64 + kc * 32)
                       : (w_hh2 + g * 64 + (kc - 2) * 32);
      }
      float tmp[32];
      #pragma unroll
      for (int q = 0; q < 8; ++q) {
        float4 v = ((const float4*)src)[q];
        tmp[4*q+0] = v.x; tmp[4*q+1] = v.y; tmp[4*q+2] = v.z; tmp[4*q+3] = v.w;
      }
      #pragma unroll
      for (int jj = 0; jj < 16; ++jj) {
        half2_t h; h[0] = (_Float16)tmp[2*jj]; h[1] = (_Float16)tmp[2*jj+1];
        wr[r][jj] = h;
      }
    }
  }

  // LDS source pointer for this thread's k-chunk (even/odd phase for L1 kc0)
  const _Float16* sEven = h1h;
  const _Float16* sOdd  = h1h;
  if (isL1) {
    if (kc == 0)      { sEven = xh[0]; sOdd = xh[1]; }
    else if (kc == 1) { sEven = h1h;      sOdd = h1h; }
    else              { sEven = h1h + 32; sOdd = h1h + 32; }
  } else if (isMM) {
    const _Float16* p_ = (kc == 0) ? h1h : (kc == 1) ? (h1h + 32)
                       : (kc == 2) ? h2h : (h2h + 32);
    sEven = p_; sOdd = p_;
  }
  float* ptw = isMM ? (isL1 ? &pt1[kc][rg * 8] : &pt2[kc][rg * 8]) : &pt1[0][0];

  __syncthreads();

  float c1 = 0.0f, c2 = 0.0f;  // owner cell state registers

  // ---- main recurrence: phases 0..T; phase p does L1@t=p and L2@t=p-1 ----
  for (int p = 0; p <= T_STEPS; ++p) {
    if (isMM) {
      const _Float16* sp = (p & 1) ? sOdd : sEven;
      const float4* s4 = (const float4*)sp;
      float4 v0 = s4[0], v1 = s4[1], v2 = s4[2], v3 = s4[3];
      half2_t sh[16];
      sh[0]=f_as_h2(v0.x);  sh[1]=f_as_h2(v0.y);  sh[2]=f_as_h2(v0.z);  sh[3]=f_as_h2(v0.w);
      sh[4]=f_as_h2(v1.x);  sh[5]=f_as_h2(v1.y);  sh[6]=f_as_h2(v1.z);  sh[7]=f_as_h2(v1.w);
      sh[8]=f_as_h2(v2.x);  sh[9]=f_as_h2(v2.y);  sh[10]=f_as_h2(v2.z); sh[11]=f_as_h2(v2.w);
      sh[12]=f_as_h2(v3.x); sh[13]=f_as_h2(v3.y); sh[14]=f_as_h2(v3.z); sh[15]=f_as_h2(v3.w);
      float acc[8] = {0,0,0,0,0,0,0,0};
      #pragma unroll
      for (int jj = 0; jj < 16; ++jj) {
        #pragma unroll
        for (int r = 0; r < 8; ++r) acc[r] = dot2(wr[r][jj], sh[jj], acc[r]);
      }
      float4* pw = (float4*)ptw;
      pw[0] = make_float4(acc[0], acc[1], acc[2], acc[3]);
      pw[1] = make_float4(acc[4], acc[5], acc[6], acc[7]);
    } else {
      // x prefetch lanes: load x_{p+1} and stage into the other buffer
      if (p + 1 < T_STEPS) {
        float xv = x[(size_t)b * (T_STEPS * IN) + (size_t)(p + 1) * IN + (t - 224)];
        xh[(p + 1) & 1][t - 224] = (_Float16)xv;
      }
    }
    __syncthreads();

    if (t < 64) {
      // layer-1 owner for unit j = t : produces h1_p   (p==T result is unused garbage)
      const int j = t;
      float pi = pt1[0][j]       + pt1[1][j]       + pt1[2][j]       + bsum1[j];
      float pf = pt1[0][64 + j]  + pt1[1][64 + j]  + pt1[2][64 + j]  + bsum1[64 + j];
      float pg = pt1[0][128 + j] + pt1[1][128 + j] + pt1[2][128 + j] + bsum1[128 + j];
      float po = pt1[0][192 + j] + pt1[1][192 + j] + pt1[2][192 + j] + bsum1[192 + j];
      float ii = sigm(pi), ff = sigm(pf), gg = tanh_(pg), oo = sigm(po);
      c1 = ff * c1 + ii * gg;
      float hn = oo * tanh_(c1);
      h1h[j] = (_Float16)hn;
    } else if (t < 128 && p > 0) {
      // layer-2 owner for unit j : produces h2_{p-1}
      const int j = t - 64;
      float pi = pt2[0][j]       + pt2[1][j]       + pt2[2][j]       + pt2[3][j]       + bsum2[j];
      float pf = pt2[0][64 + j]  + pt2[1][64 + j]  + pt2[2][64 + j]  + pt2[3][64 + j]  + bsum2[64 + j];
      float pg = pt2[0][128 + j] + pt2[1][128 + j] + pt2[2][128 + j] + pt2[3][128 + j] + bsum2[128 + j];
      float po = pt2[0][192 + j] + pt2[1][192 + j] + pt2[2][192 + j] + pt2[3][192 + j] + bsum2[192 + j];
      float ii = sigm(pi), ff = sigm(pf), gg = tanh_(pg), oo = sigm(po);
      c2 = ff * c2 + ii * gg;
      float hn = oo * tanh_(c2);
      h2h[j] = (_Float16)hn;
      if (p == T_STEPS) hfin[j] = hn;  // final h2 (t = T-1) in f32
    }
    __syncthreads();
  }

  // ---- head: y = LN(relu(hT@fc1^T+b1)@fc2^T+b2) ----
  if (t < 128) {
    float a = fc1_b[t];
    const float4* w4 = (const float4*)(fc1_w + t * 64);
    const float4* h4 = (const float4*)hfin;
    #pragma unroll
    for (int q = 0; q < 16; ++q) {
      float4 wv = w4[q]; float4 hv = h4[q];
      a += wv.x * hv.x + wv.y * hv.y + wv.z * hv.z + wv.w * hv.w;
    }
    y1s[t] = fmaxf(a, 0.0f);
  }
  __syncthreads();
  if (t < 128) {
    float a = fc2_b[t];
    const float4* w4 = (const float4*)(fc2_w + t * 128);
    const float4* y4 = (const float4*)y1s;
    #pragma unroll
    for (int q = 0; q < 32; ++q) {
      float4 wv = w4[q]; float4 yv = y4[q];
      a += wv.x * yv.x + wv.y * yv.y + wv.z * yv.z + wv.w * yv.w;
    }
    y2s[t] = a;
  }
  __syncthreads();
  if (t < 64) {
    float s = y2s[t] + y2s[t + 64];
    float q = y2s[t] * y2s[t] + y2s[t + 64] * y2s[t + 64];
    #pragma unroll
    for (int off = 32; off > 0; off >>= 1) {
      s += __shfl_down(s, off);
      q += __shfl_down(q, off);
    }
    if (t == 0) {
      float mu  = s * (1.0f / 128.0f);
      float var = q * (1.0f / 128.0f) - mu * mu;
      redmu = mu;
      redrs = rsqrtf(var + 1e-5f);
    }
  }
  __syncthreads();
  if (t < 128) {
    out[(size_t)b * 128 + t] = (y2s[t] - redmu) * redrs * ln_g[t] + ln_b[t];
  }
}

extern "C" void kernel_launch(void* const* d_in, const int* in_sizes, int n_in,
                              void* d_out, int out_size, void* d_ws, size_t ws_size,
                              hipStream_t stream) {
  const float* x     = (const float*)d_in[0];
  const float* w_ih1 = (const float*)d_in[1];
  const float* w_hh1 = (const float*)d_in[2];
  const float* b_ih1 = (const float*)d_in[3];
  const float* b_hh1 = (const float*)d_in[4];
  const float* w_ih2 = (const float*)d_in[5];
  const float* w_hh2 = (const float*)d_in[6];
  const float* b_ih2 = (const float*)d_in[7];
  const float* b_hh2 = (const float*)d_in[8];
  const float* fc1_w = (const float*)d_in[9];
  const float* fc1_b = (const float*)d_in[10];
  const float* fc2_w = (const float*)d_in[11];
  const float* fc2_b = (const float*)d_in[12];
  const float* ln_g  = (const float*)d_in[13];
  const float* ln_b  = (const float*)d_in[14];
  float* out = (float*)d_out;

  lstm_fused<<<BATCH, 256, 0, stream>>>(x, w_ih1, w_hh1, b_ih1, b_hh1,
                                        w_ih2, w_hh2, b_ih2, b_hh2,
                                        fc1_w, fc1_b, fc2_w, fc2_b,
                                        ln_g, ln_b, out);
}

// Round 2
// 1069.429 us; speedup vs baseline: 1.1145x; 1.1145x over previous
//
#include <hip/hip_runtime.h>
#include <cstdint>
#include <cstddef>

#define T_STEPS 1024
#define BATCH   512

typedef __attribute__((ext_vector_type(2))) _Float16 half2_t;

static __device__ __forceinline__ half2_t f_as_h2(float f) {
  union { float f; half2_t h; } u; u.f = f; return u.h;
}
static __device__ __forceinline__ half2_t mk_h2(float a, float b) {
  half2_t h; h[0] = (_Float16)a; h[1] = (_Float16)b; return h;
}

static __device__ __forceinline__ float dot2(half2_t a, half2_t b, float c) {
#if defined(__has_builtin)
#if __has_builtin(__builtin_amdgcn_fdot2)
  return __builtin_amdgcn_fdot2(a, b, c, false);
#else
  return c + (float)a[0]*(float)b[0] + (float)a[1]*(float)b[1];
#endif
#else
  return c + (float)a[0]*(float)b[0] + (float)a[1]*(float)b[1];
#endif
}

// sigmoid / tanh via exp+rcp (validated: absmax 0.016 in R1)
static __device__ __forceinline__ float tanh_(float x) {
  return 1.0f - 2.0f * __builtin_amdgcn_rcpf(__expf(2.0f * x) + 1.0f);
}
// gate activation: sigmoid for i,f,o; tanh for g (tanh(v) = 2*sigm(2v)-1)
static __device__ __forceinline__ float gact(float v, bool isg) {
  float arg = isg ? (v + v) : v;
  float s = __builtin_amdgcn_rcpf(1.0f + __expf(-arg));
  return isg ? (s + s - 1.0f) : s;
}

// quad broadcast: every lane gets the value from lane (quadbase + K). Pure VALU (DPP).
template <int K>
static __device__ __forceinline__ float qbcast(float v) {
#if defined(__has_builtin) && __has_builtin(__builtin_amdgcn_update_dpp)
  union { float f; int i; } a, r;
  a.f = v;
  r.i = __builtin_amdgcn_update_dpp(0, a.i, K * 0x55, 0xF, 0xF, true);
  return r.f;
#else
  int lane = (int)(threadIdx.x & 63);
  return __shfl(v, (lane & ~3) + K, 64);
#endif
}

// One batch element per block; grid = 512 blocks (2/CU).
// Lane layout: l = tid&63, w = tid>>6; gate type k = l&3; unit u = w*16 + (l>>2).
// Thread computes L1 gate (row k*64+u) AND L2 gate (same row), full K each.
// After activation, DPP quad_perm broadcasts the 4 gates within the quad; c1/c2
// replicated across the quad. ONE __syncthreads per phase.
__global__ __launch_bounds__(256, 2) void lstm_fused(
    const float* __restrict__ x,
    const float* __restrict__ w_ih1, const float* __restrict__ w_hh1,
    const float* __restrict__ b_ih1, const float* __restrict__ b_hh1,
    const float* __restrict__ w_ih2, const float* __restrict__ w_hh2,
    const float* __restrict__ b_ih2, const float* __restrict__ b_hh2,
    const float* __restrict__ fc1_w, const float* __restrict__ fc1_b,
    const float* __restrict__ fc2_w, const float* __restrict__ fc2_b,
    const float* __restrict__ ln_g, const float* __restrict__ ln_b,
    float* __restrict__ out)
{
  // b1[buf][0:32) = x_t slot (f16), b1[buf][32:96) = h1 (f16). Double-buffered.
  __shared__ __align__(16) _Float16 b1[2][96];
  __shared__ __align__(16) _Float16 h2b[2][64];
  __shared__ __align__(16) float hfin[64];
  __shared__ __align__(16) float y1s[128];
  __shared__ __align__(16) float y2s[128];
  __shared__ float redmu, redrs;

  const int t = threadIdx.x;
  const int b = blockIdx.x;
  const int l = t & 63;
  const int w = t >> 6;
  const int k = l & 3;                 // gate type: 0=i 1=f 2=g 3=o
  const int u = w * 16 + (l >> 2);     // unit 0..63
  const int row = k * 64 + u;          // weight row in [0,256)
  const bool isg = (k == 2);

  // ---- init LDS state ----
  if (t < 64) { b1[1][32 + t] = (_Float16)0.0f; h2b[0][t] = (_Float16)0.0f; h2b[1][t] = (_Float16)0.0f; }
  if (t < 32) { b1[1][t] = (_Float16)x[(size_t)b * (T_STEPS * 32) + t]; }  // x_0

  // ---- stationary weights -> registers as f16 pairs ----
  half2_t wx1[16];   // w_ih1[row, 0:32]
  half2_t wh1[32];   // w_hh1[row, 0:64]
  half2_t wi2[32];   // w_ih2[row, 0:64]
  half2_t wh2[32];   // w_hh2[row, 0:64]
  {
    const float4* s = (const float4*)(w_ih1 + row * 32);
    #pragma unroll
    for (int q = 0; q < 8; ++q) { float4 v = s[q]; wx1[2*q] = mk_h2(v.x, v.y); wx1[2*q+1] = mk_h2(v.z, v.w); }
  }
  {
    const float4* s = (const float4*)(w_hh1 + row * 64);
    #pragma unroll
    for (int q = 0; q < 16; ++q) { float4 v = s[q]; wh1[2*q] = mk_h2(v.x, v.y); wh1[2*q+1] = mk_h2(v.z, v.w); }
  }
  {
    const float4* s = (const float4*)(w_ih2 + row * 64);
    #pragma unroll
    for (int q = 0; q < 16; ++q) { float4 v = s[q]; wi2[2*q] = mk_h2(v.x, v.y); wi2[2*q+1] = mk_h2(v.z, v.w); }
  }
  {
    const float4* s = (const float4*)(w_hh2 + row * 64);
    #pragma unroll
    for (int q = 0; q < 16; ++q) { float4 v = s[q]; wh2[2*q] = mk_h2(v.x, v.y); wh2[2*q+1] = mk_h2(v.z, v.w); }
  }
  const float bs1 = b_ih1[row] + b_hh1[row];
  const float bs2 = b_ih2[row] + b_hh2[row];

  const float* xnextp = x + (size_t)b * (T_STEPS * 32) + 32 + t;  // x[b, p+1, t] for t<32

  __syncthreads();

  float c1 = 0.0f, c2 = 0.0f;  // replicated within each quad

  for (int p = 0; p <= T_STEPS; ++p) {
    const int rdi = (p + 1) & 1;
    const int wri = p & 1;

    // x prefetch: lanes 0..31 load x_{p+1} (consumed next phase)
    const bool doload = (t < 32) && (p + 1 < T_STEPS);
    float xnext = 0.0f;
    if (doload) xnext = xnextp[(size_t)p * 32];

    const half2_t* s1 = (const half2_t*)b1[rdi];    // [0:16)=x, [16:48)=h1
    const half2_t* s2 = (const half2_t*)h2b[rdi];   // h2

    float a1 = bs1, a2 = bs2;
    #pragma unroll
    for (int q = 0; q < 16; ++q) a1 = dot2(wx1[q], s1[q], a1);
    #pragma unroll
    for (int q = 0; q < 32; ++q) { half2_t hv = s1[16 + q]; a1 = dot2(wh1[q], hv, a1); a2 = dot2(wi2[q], hv, a2); }
    #pragma unroll
    for (int q = 0; q < 32; ++q) a2 = dot2(wh2[q], s2[q], a2);

    // per-lane activation, then quad-broadcast all 4 gates (DPP, no LDS)
    const float g1 = gact(a1, isg);
    const float g2 = gact(a2, isg);
    const float i1 = qbcast<0>(g1), f1 = qbcast<1>(g1), gg1 = qbcast<2>(g1), o1 = qbcast<3>(g1);
    const float i2 = qbcast<0>(g2), f2 = qbcast<1>(g2), gg2 = qbcast<2>(g2), o2 = qbcast<3>(g2);

    // L1 cell update (replicated in quad); h1_p -> LDS
    c1 = f1 * c1 + i1 * gg1;
    const float h1v = o1 * tanh_(c1);
    if (k == 0) b1[wri][32 + u] = (_Float16)h1v;

    // L2 cell update (t = p-1); skip at p==0
    if (p > 0) {
      c2 = f2 * c2 + i2 * gg2;
      const float h2v = o2 * tanh_(c2);
      if (k == 0) {
        h2b[wri][u] = (_Float16)h2v;
        if (p == T_STEPS) hfin[u] = h2v;   // h2_{T-1} in f32 for the head
      }
    }

    // stage x_{p+1} into the write buffer
    if (doload) b1[wri][t] = (_Float16)xnext;

    __syncthreads();
  }

  // ---- head: y = LN(relu(hT@fc1^T+b1)@fc2^T+b2) ----
  if (t < 128) {
    float a = fc1_b[t];
    const float4* w4 = (const float4*)(fc1_w + t * 64);
    const float4* h4 = (const float4*)hfin;
    #pragma unroll
    for (int q = 0; q < 16; ++q) {
      float4 wv = w4[q]; float4 hv = h4[q];
      a += wv.x * hv.x + wv.y * hv.y + wv.z * hv.z + wv.w * hv.w;
    }
    y1s[t] = fmaxf(a, 0.0f);
  }
  __syncthreads();
  if (t < 128) {
    float a = fc2_b[t];
    const float4* w4 = (const float4*)(fc2_w + t * 128);
    const float4* y4 = (const float4*)y1s;
    #pragma unroll
    for (int q = 0; q < 32; ++q) {
      float4 wv = w4[q]; float4 yv = y4[q];
      a += wv.x * yv.x + wv.y * yv.y + wv.z * yv.z + wv.w * yv.w;
    }
    y2s[t] = a;
  }
  __syncthreads();
  if (t < 64) {
    float s = y2s[t] + y2s[t + 64];
    float q = y2s[t] * y2s[t] + y2s[t + 64] * y2s[t + 64];
    #pragma unroll
    for (int off = 32; off > 0; off >>= 1) {
      s += __shfl_down(s, off);
      q += __shfl_down(q, off);
    }
    if (t == 0) {
      float mu  = s * (1.0f / 128.0f);
      float var = q * (1.0f / 128.0f) - mu * mu;
      redmu = mu;
      redrs = rsqrtf(var + 1e-5f);
    }
  }
  __syncthreads();
  if (t < 128) {
    out[(size_t)b * 128 + t] = (y2s[t] - redmu) * redrs * ln_g[t] + ln_b[t];
  }
}

extern "C" void kernel_launch(void* const* d_in, const int* in_sizes, int n_in,
                              void* d_out, int out_size, void* d_ws, size_t ws_size,
                              hipStream_t stream) {
  const float* x     = (const float*)d_in[0];
  const float* w_ih1 = (const float*)d_in[1];
  const float* w_hh1 = (const float*)d_in[2];
  const float* b_ih1 = (const float*)d_in[3];
  const float* b_hh1 = (const float*)d_in[4];
  const float* w_ih2 = (const float*)d_in[5];
  const float* w_hh2 = (const float*)d_in[6];
  const float* b_ih2 = (const float*)d_in[7];
  const float* b_hh2 = (const float*)d_in[8];
  const float* fc1_w = (const float*)d_in[9];
  const float* fc1_b = (const float*)d_in[10];
  const float* fc2_w = (const float*)d_in[11];
  const float* fc2_b = (const float*)d_in[12];
  const float* ln_g  = (const float*)d_in[13];
  const float* ln_b  = (const float*)d_in[14];
  float* out = (float*)d_out;

  lstm_fused<<<BATCH, 256, 0, stream>>>(x, w_ih1, w_hh1, b_ih1, b_hh1,
                                        w_ih2, w_hh2, b_ih2, b_hh2,
                                        fc1_w, fc1_b, fc2_w, fc2_b,
                                        ln_g, ln_b, out);
}

// Round 3
// 1043.692 us; speedup vs baseline: 1.1420x; 1.0247x over previous
//
#include <hip/hip_runtime.h>
#include <cstdint>
#include <cstddef>

#define T_STEPS 1024
#define BATCH   512

typedef __attribute__((ext_vector_type(2))) _Float16 half2_t;

static __device__ __forceinline__ half2_t f_as_h2(float f) {
  union { float f; half2_t h; } u; u.f = f; return u.h;
}
static __device__ __forceinline__ half2_t mk_h2(float a, float b) {
  half2_t h; h[0] = (_Float16)a; h[1] = (_Float16)b; return h;
}

static __device__ __forceinline__ float dot2(half2_t a, half2_t b, float c) {
#if defined(__has_builtin)
#if __has_builtin(__builtin_amdgcn_fdot2)
  return __builtin_amdgcn_fdot2(a, b, c, false);
#else
  return c + (float)a[0]*(float)b[0] + (float)a[1]*(float)b[1];
#endif
#else
  return c + (float)a[0]*(float)b[0] + (float)a[1]*(float)b[1];
#endif
}

static __device__ __forceinline__ float tanh_(float x) {
  return 1.0f - 2.0f * __builtin_amdgcn_rcpf(__expf(2.0f * x) + 1.0f);
}
// sigmoid for i,f,o; tanh for g via tanh(v) = 2*sigm(2v)-1
static __device__ __forceinline__ float gact(float v, bool isg) {
  float arg = isg ? (v + v) : v;
  float s = __builtin_amdgcn_rcpf(1.0f + __expf(-arg));
  return isg ? (s + s - 1.0f) : s;
}

// quad broadcast via DPP quad_perm: every lane gets lane (quadbase+K)'s value.
template <int K>
static __device__ __forceinline__ float qbcast(float v) {
#if defined(__has_builtin) && __has_builtin(__builtin_amdgcn_update_dpp)
  union { float f; int i; } a, r;
  a.f = v;
  r.i = __builtin_amdgcn_update_dpp(0, a.i, K * 0x55, 0xF, 0xF, true);
  return r.f;
#else
  int lane = (int)(threadIdx.x & 63);
  return __shfl(v, (lane & ~3) + K, 64);
#endif
}

// 512 threads/block, 1 batch element/block, grid=512 (2 blocks/CU, 16 waves/CU).
// Threads [0,256)   = layer-1 group: thread owns gate row k*64+u of L1 (K=96+16pad).
// Threads [256,512) = layer-2 group: same row of L2 (K=128).
// State vector in LDS (f16, double-buffered): [ x_t(32) | h1(64) | h2(64) ].
// L1 threads dot over halves [0,128) with wt[48..63]=0; L2 over [32,160).
// Unified code path: 16 ds_read_b128 broadcasts + 64 v_dot2_f32_f16 per thread.
// Gates exchanged within lane-quads via DPP; one __syncthreads per phase.
__global__ __launch_bounds__(512, 4) void lstm_fused(
    const float* __restrict__ x,
    const float* __restrict__ w_ih1, const float* __restrict__ w_hh1,
    const float* __restrict__ b_ih1, const float* __restrict__ b_hh1,
    const float* __restrict__ w_ih2, const float* __restrict__ w_hh2,
    const float* __restrict__ b_ih2, const float* __restrict__ b_hh2,
    const float* __restrict__ fc1_w, const float* __restrict__ fc1_b,
    const float* __restrict__ fc2_w, const float* __restrict__ fc2_b,
    const float* __restrict__ ln_g, const float* __restrict__ ln_b,
    float* __restrict__ out)
{
  __shared__ __align__(16) _Float16 buf[2][160];  // [x|h1|h2], double-buffered
  __shared__ __align__(16) float hfin[64];
  __shared__ __align__(16) float y1s[128];
  __shared__ __align__(16) float y2s[128];
  __shared__ float redmu, redrs;

  const int t = threadIdx.x;
  const int b = blockIdx.x;
  const bool isL1 = (t < 256);
  const int tl = t & 255;
  const int l  = t & 63;
  const int k  = l & 3;                    // gate: 0=i 1=f 2=g 3=o
  const int u  = (tl >> 6) * 16 + (l >> 2);  // unit 0..63
  const int row = k * 64 + u;
  const bool isg = (k == 2);

  // ---- init LDS state: h1 = h2 = 0 in both buffers; x_0 into buf[1] ----
  if (t < 64) {
    buf[0][32 + t] = (_Float16)0.0f; buf[1][32 + t] = (_Float16)0.0f;
    buf[0][96 + t] = (_Float16)0.0f; buf[1][96 + t] = (_Float16)0.0f;
  }
  if (t < 32) buf[1][t] = (_Float16)x[(size_t)b * (T_STEPS * 32) + t];

  // ---- stationary weights: one gate row, packed f16 pairs (64 dwords) ----
  half2_t wt[64];
  if (isL1) {
    const float4* s = (const float4*)(w_ih1 + row * 32);
    #pragma unroll
    for (int q = 0; q < 8; ++q)  { float4 v = s[q]; wt[2*q]    = mk_h2(v.x, v.y); wt[2*q+1]    = mk_h2(v.z, v.w); }
    const float4* h = (const float4*)(w_hh1 + row * 64);
    #pragma unroll
    for (int q = 0; q < 16; ++q) { float4 v = h[q]; wt[16+2*q] = mk_h2(v.x, v.y); wt[16+2*q+1] = mk_h2(v.z, v.w); }
    #pragma unroll
    for (int q = 48; q < 64; ++q) wt[q] = mk_h2(0.0f, 0.0f);
  } else {
    const float4* s = (const float4*)(w_ih2 + row * 64);
    #pragma unroll
    for (int q = 0; q < 16; ++q) { float4 v = s[q]; wt[2*q]    = mk_h2(v.x, v.y); wt[2*q+1]    = mk_h2(v.z, v.w); }
    const float4* h = (const float4*)(w_hh2 + row * 64);
    #pragma unroll
    for (int q = 0; q < 16; ++q) { float4 v = h[q]; wt[32+2*q] = mk_h2(v.x, v.y); wt[32+2*q+1] = mk_h2(v.z, v.w); }
  }
  const float bs = isL1 ? (b_ih1[row] + b_hh1[row]) : (b_ih2[row] + b_hh2[row]);

  const int soff = isL1 ? 0 : 32;    // source base (halves)
  const int hoff = isL1 ? 32 : 96;   // h write slot (halves)
  const float* xnextp = x + (size_t)b * (T_STEPS * 32) + 32 + t;  // x[b,p+1,t], t<32

  __syncthreads();

  float c = 0.0f;  // cell state, replicated within each quad

  for (int p = 0; p <= T_STEPS; ++p) {
    const int rdi = (p + 1) & 1;
    const int wri = p & 1;

    const bool doload = (t < 32) && (p + 1 < T_STEPS);
    float xn = 0.0f;
    if (doload) xn = xnextp[(size_t)p * 32];

    const float4* s4 = (const float4*)(&buf[rdi][soff]);
    float a0 = 0.0f, a1 = 0.0f, a2 = 0.0f, a3 = 0.0f;
    #pragma unroll
    for (int q = 0; q < 16; ++q) {
      float4 v = s4[q];
      a0 = dot2(wt[4*q+0], f_as_h2(v.x), a0);
      a1 = dot2(wt[4*q+1], f_as_h2(v.y), a1);
      a2 = dot2(wt[4*q+2], f_as_h2(v.z), a2);
      a3 = dot2(wt[4*q+3], f_as_h2(v.w), a3);
    }
    const float a = bs + ((a0 + a1) + (a2 + a3));

    const float g = gact(a, isg);
    const float gi = qbcast<0>(g), gf = qbcast<1>(g), gg = qbcast<2>(g), go = qbcast<3>(g);

    if (isL1 || p > 0) {   // L2's phase-0 output (h2_{-1}) doesn't exist
      c = gf * c + gi * gg;
      const float hv = go * tanh_(c);
      if (k == 0) {
        buf[wri][hoff + u] = (_Float16)hv;
        if (!isL1 && p == T_STEPS) hfin[u] = hv;  // h2_{T-1} in f32
      }
    }

    if (doload) buf[wri][t] = (_Float16)xn;  // stage x_{p+1}
    __syncthreads();
  }

  // ---- head: y = LN(relu(hT@fc1^T+b1)@fc2^T+b2) ----
  if (t < 128) {
    float a = fc1_b[t];
    const float4* w4 = (const float4*)(fc1_w + t * 64);
    const float4* h4 = (const float4*)hfin;
    #pragma unroll
    for (int q = 0; q < 16; ++q) {
      float4 wv = w4[q]; float4 hv = h4[q];
      a += wv.x * hv.x + wv.y * hv.y + wv.z * hv.z + wv.w * hv.w;
    }
    y1s[t] = fmaxf(a, 0.0f);
  }
  __syncthreads();
  if (t < 128) {
    float a = fc2_b[t];
    const float4* w4 = (const float4*)(fc2_w + t * 128);
    const float4* y4 = (const float4*)y1s;
    #pragma unroll
    for (int q = 0; q < 32; ++q) {
      float4 wv = w4[q]; float4 yv = y4[q];
      a += wv.x * yv.x + wv.y * yv.y + wv.z * yv.z + wv.w * yv.w;
    }
    y2s[t] = a;
  }
  __syncthreads();
  if (t < 64) {
    float s = y2s[t] + y2s[t + 64];
    float q = y2s[t] * y2s[t] + y2s[t + 64] * y2s[t + 64];
    #pragma unroll
    for (int off = 32; off > 0; off >>= 1) {
      s += __shfl_down(s, off);
      q += __shfl_down(q, off);
    }
    if (t == 0) {
      float mu  = s * (1.0f / 128.0f);
      float var = q * (1.0f / 128.0f) - mu * mu;
      redmu = mu;
      redrs = rsqrtf(var + 1e-5f);
    }
  }
  __syncthreads();
  if (t < 128) {
    out[(size_t)b * 128 + t] = (y2s[t] - redmu) * redrs * ln_g[t] + ln_b[t];
  }
}

extern "C" void kernel_launch(void* const* d_in, const int* in_sizes, int n_in,
                              void* d_out, int out_size, void* d_ws, size_t ws_size,
                              hipStream_t stream) {
  const float* x     = (const float*)d_in[0];
  const float* w_ih1 = (const float*)d_in[1];
  const float* w_hh1 = (const float*)d_in[2];
  const float* b_ih1 = (const float*)d_in[3];
  const float* b_hh1 = (const float*)d_in[4];
  const float* w_ih2 = (const float*)d_in[5];
  const float* w_hh2 = (const float*)d_in[6];
  const float* b_ih2 = (const float*)d_in[7];
  const float* b_hh2 = (const float*)d_in[8];
  const float* fc1_w = (const float*)d_in[9];
  const float* fc1_b = (const float*)d_in[10];
  const float* fc2_w = (const float*)d_in[11];
  const float* fc2_b = (const float*)d_in[12];
  const float* ln_g  = (const float*)d_in[13];
  const float* ln_b  = (const float*)d_in[14];
  float* out = (float*)d_out;

  lstm_fused<<<BATCH, 512, 0, stream>>>(x, w_ih1, w_hh1, b_ih1, b_hh1,
                                        w_ih2, w_hh2, b_ih2, b_hh2,
                                        fc1_w, fc1_b, fc2_w, fc2_b,
                                        ln_g, ln_b, out);
}

// Round 4
// 771.320 us; speedup vs baseline: 1.5452x; 1.3531x over previous
//
#include <hip/hip_runtime.h>
#include <cstdint>
#include <cstddef>

#define T_STEPS 1024
#define NBLK    256   // 512 batch / 2 per block

typedef __attribute__((ext_vector_type(8))) _Float16 half8;
typedef __attribute__((ext_vector_type(4))) float    f32x4;

static __device__ __forceinline__ float sigm(float x) {
  return __builtin_amdgcn_rcpf(1.0f + __expf(-x));
}
static __device__ __forceinline__ float tanh_(float x) {
  return 1.0f - 2.0f * __builtin_amdgcn_rcpf(__expf(2.0f * x) + 1.0f);
}

static __device__ __forceinline__ half8 load8(const float* s) {
  float4 a = ((const float4*)s)[0];
  float4 b = ((const float4*)s)[1];
  half8 h;
  h[0] = (_Float16)a.x; h[1] = (_Float16)a.y; h[2] = (_Float16)a.z; h[3] = (_Float16)a.w;
  h[4] = (_Float16)b.x; h[5] = (_Float16)b.y; h[6] = (_Float16)b.z; h[7] = (_Float16)b.w;
  return h;
}
static __device__ __forceinline__ half8 zero8() {
  half8 h;
  #pragma unroll
  for (int j = 0; j < 8; ++j) h[j] = (_Float16)0.0f;
  return h;
}

// Grid 256 blocks x 512 threads; block handles batch rows 2b, 2b+1 (M=2 of 16 MFMA rows).
// Waves 0-3: L1 GEMM (gates 64w..64w+63), waves 4-7: L2 GEMM. Weights stationary as
// MFMA B-fragments in VGPRs (L1 K=96 zero-padded to 128). State S=[x(32)|h1(64)|h2(64)]
// f16 in LDS, double-buffered; A-frags = 4 ds_read_b128/wave/phase.
// Software pipeline: phase p computes L1@t=p (needs x_p,h1_{p-1}) and L2@t=p-1
// (needs h1_{p-1},h2_{p-2}). Gates dumped raw to LDS; 256 act threads (one per
// layer x batch x unit, cell state c in reg) apply bias+activations, write h (f16).
// MFMA layouts (m89/m120-verified): A[m=l&15][k=(l>>4)*8+j]; B[k=(l>>4)*8+j][n=l&15];
// D[row=(l>>4)*4+reg][col=l&15]; batch rows are D rows 0,1 (lanes 0-15, regs 0,1).
__global__ __launch_bounds__(512, 2) void lstm_fused(
    const float* __restrict__ x,
    const float* __restrict__ w_ih1, const float* __restrict__ w_hh1,
    const float* __restrict__ b_ih1, const float* __restrict__ b_hh1,
    const float* __restrict__ w_ih2, const float* __restrict__ w_hh2,
    const float* __restrict__ b_ih2, const float* __restrict__ b_hh2,
    const float* __restrict__ fc1_w, const float* __restrict__ fc1_b,
    const float* __restrict__ fc2_w, const float* __restrict__ fc2_b,
    const float* __restrict__ ln_g, const float* __restrict__ ln_b,
    float* __restrict__ out)
{
  __shared__ __align__(16) _Float16 S[2][2][160];   // [buf][batch][x|h1|h2]
  __shared__ __align__(16) float G[2][2][256];      // [layer][batch][gate] raw pre-acts
  __shared__ __align__(16) float hfin[2][64];
  __shared__ __align__(16) float y1s[2][128];
  __shared__ __align__(16) float y2s[2][128];
  __shared__ float redmu[2], redrs[2];

  const int t   = threadIdx.x;
  const int b   = blockIdx.x;
  const int l   = t & 63;
  const int w   = t >> 6;       // wave 0..7
  const int ly  = w >> 2;       // GEMM layer group: 0=L1, 1=L2
  const int wq  = w & 3;        // wave within layer group
  const int col = l & 15;
  const int q   = l >> 4;       // quad

  // ---- init state: h1=h2=0 in both buffers ----
  if (t < 256) {
    const int bf = t >> 7, m = (t >> 6) & 1, uu = t & 63;
    S[bf][m][32 + uu] = (_Float16)0.0f;
    S[bf][m][96 + uu] = (_Float16)0.0f;
  }
  const bool isx = (t >= 256 && t < 320);
  const int  xm  = (t >> 5) & 1;   // batch for x-prefetch lanes
  const int  xi  = t & 31;
  const float* xp = x + ((size_t)(2 * b + xm)) * (T_STEPS * 32) + xi;
  if (isx) S[1][xm][xi] = (_Float16)xp[0];   // x_0 into read buffer of phase 0

  // ---- stationary weights -> B fragments: wb[kstep][tile] ----
  half8 wb[4][4];
  {
    const int ko = q * 8;   // k offset within a 32-wide step (0,8,16,24)
    #pragma unroll
    for (int tt = 0; tt < 4; ++tt) {
      const int r = (wq * 4 + tt) * 16 + col;   // gate row 0..255
      if (ly == 0) {
        wb[0][tt] = load8(w_ih1 + r * 32 + ko);        // k 0..31  -> x
        wb[1][tt] = load8(w_hh1 + r * 64 + ko);        // k 32..63 -> h1[0:32)
        wb[2][tt] = load8(w_hh1 + r * 64 + 32 + ko);   // k 64..95 -> h1[32:64)
        wb[3][tt] = zero8();                           // k 96..127 zero pad
      } else {
        wb[0][tt] = load8(w_ih2 + r * 64 + ko);        // k 0..31   -> h1[0:32)
        wb[1][tt] = load8(w_ih2 + r * 64 + 32 + ko);   // k 32..63  -> h1[32:64)
        wb[2][tt] = load8(w_hh2 + r * 64 + ko);        // k 64..95  -> h2[0:32)
        wb[3][tt] = load8(w_hh2 + r * 64 + 32 + ko);   // k 96..127 -> h2[32:64)
      }
    }
  }

  // ---- activation-thread setup (t<256): one (layer, batch, unit) each ----
  const int aly = t >> 7, am = (t >> 6) & 1, au = t & 63;
  float bia[4] = {0.f, 0.f, 0.f, 0.f};
  if (t < 256) {
    const float* bi_ = aly ? b_ih2 : b_ih1;
    const float* bh_ = aly ? b_hh2 : b_hh1;
    #pragma unroll
    for (int k2 = 0; k2 < 4; ++k2) bia[k2] = bi_[k2 * 64 + au] + bh_[k2 * 64 + au];
  }

  float xr = 0.0f;
  if (isx) xr = xp[32];   // x_1 (written during phase 0)

  float c = 0.0f;         // cell state for act threads
  __syncthreads();

  for (int p = 0; p <= T_STEPS; ++p) {
    const int rd = (p + 1) & 1;
    const int wr = p & 1;

    // prefetch x two steps ahead (register pipeline hides HBM latency)
    float xr2 = 0.0f;
    if (isx && p + 2 < T_STEPS) xr2 = xp[(size_t)(p + 2) * 32];

    // ---- GEMM: A frags from LDS, 16 MFMA (4 tiles x 4 ksteps) ----
    const char* ab = (const char*)(&S[rd][0][0]) + (col & 1) * 320 + ly * 64 + q * 16;
    half8 af[4];
    #pragma unroll
    for (int ks = 0; ks < 4; ++ks) af[ks] = *(const half8*)(ab + ks * 64);
    f32x4 acc[4];
    #pragma unroll
    for (int tt = 0; tt < 4; ++tt) acc[tt] = (f32x4){0.f, 0.f, 0.f, 0.f};
    #pragma unroll
    for (int ks = 0; ks < 4; ++ks) {
      #pragma unroll
      for (int tt = 0; tt < 4; ++tt)
        acc[tt] = __builtin_amdgcn_mfma_f32_16x16x32_f16(af[ks], wb[ks][tt], acc[tt], 0, 0, 0);
    }

    // dump raw gates (batch rows = regs 0,1 of lanes 0-15)
    if (q == 0) {
      #pragma unroll
      for (int tt = 0; tt < 4; ++tt) {
        const int n = (wq * 4 + tt) * 16 + col;
        G[ly][0][n] = acc[tt][0];
        G[ly][1][n] = acc[tt][1];
      }
    }
    // stage x_{p+1} into write buffer (loaded last phase)
    if (isx && p + 1 < T_STEPS) S[wr][xm][xi] = (_Float16)xr;
    __syncthreads();

    // ---- activations: one unit per thread, c in register ----
    if (t < 256 && (aly == 0 || p > 0)) {
      const float vi = G[aly][am][au]        + bia[0];
      const float vf = G[aly][am][64 + au]   + bia[1];
      const float vg = G[aly][am][128 + au]  + bia[2];
      const float vo = G[aly][am][192 + au]  + bia[3];
      const float gi = sigm(vi), gf = sigm(vf), gg = tanh_(vg), go = sigm(vo);
      c = gf * c + gi * gg;
      const float hv = go * tanh_(c);
      S[wr][am][(aly ? 96 : 32) + au] = (_Float16)hv;
      if (aly == 1 && p == T_STEPS) hfin[am][au] = hv;   // h2_{T-1}
    }
    xr = xr2;
    __syncthreads();
  }

  // ---- head: y = LN(relu(hT@fc1^T+b1)@fc2^T+b2), 2 batch rows ----
  if (t < 256) {
    const int bi = t >> 7, j = t & 127;
    float a = fc1_b[j];
    const float4* w4 = (const float4*)(fc1_w + j * 64);
    const float4* h4 = (const float4*)hfin[bi];
    #pragma unroll
    for (int qq = 0; qq < 16; ++qq) {
      float4 wv = w4[qq]; float4 hv = h4[qq];
      a += wv.x * hv.x + wv.y * hv.y + wv.z * hv.z + wv.w * hv.w;
    }
    y1s[bi][j] = fmaxf(a, 0.0f);
  }
  __syncthreads();
  if (t < 256) {
    const int bi = t >> 7, j = t & 127;
    float a = fc2_b[j];
    const float4* w4 = (const float4*)(fc2_w + j * 128);
    const float4* y4 = (const float4*)y1s[bi];
    #pragma unroll
    for (int qq = 0; qq < 32; ++qq) {
      float4 wv = w4[qq]; float4 yv = y4[qq];
      a += wv.x * yv.x + wv.y * yv.y + wv.z * yv.z + wv.w * yv.w;
    }
    y2s[bi][j] = a;
  }
  __syncthreads();
  if (t < 128) {
    const int bi = t >> 6, jj = t & 63;
    float s = y2s[bi][jj] + y2s[bi][64 + jj];
    float qs = y2s[bi][jj] * y2s[bi][jj] + y2s[bi][64 + jj] * y2s[bi][64 + jj];
    #pragma unroll
    for (int off = 32; off > 0; off >>= 1) {
      s  += __shfl_down(s, off, 64);
      qs += __shfl_down(qs, off, 64);
    }
    if (jj == 0) {
      const float mu  = s * (1.0f / 128.0f);
      const float var = qs * (1.0f / 128.0f) - mu * mu;
      redmu[bi] = mu;
      redrs[bi] = rsqrtf(var + 1e-5f);
    }
  }
  __syncthreads();
  if (t < 256) {
    const int bi = t >> 7, j = t & 127;
    out[(size_t)(2 * b + bi) * 128 + j] =
        (y2s[bi][j] - redmu[bi]) * redrs[bi] * ln_g[j] + ln_b[j];
  }
}

extern "C" void kernel_launch(void* const* d_in, const int* in_sizes, int n_in,
                              void* d_out, int out_size, void* d_ws, size_t ws_size,
                              hipStream_t stream) {
  const float* x     = (const float*)d_in[0];
  const float* w_ih1 = (const float*)d_in[1];
  const float* w_hh1 = (const float*)d_in[2];
  const float* b_ih1 = (const float*)d_in[3];
  const float* b_hh1 = (const float*)d_in[4];
  const float* w_ih2 = (const float*)d_in[5];
  const float* w_hh2 = (const float*)d_in[6];
  const float* b_ih2 = (const float*)d_in[7];
  const float* b_hh2 = (const float*)d_in[8];
  const float* fc1_w = (const float*)d_in[9];
  const float* fc1_b = (const float*)d_in[10];
  const float* fc2_w = (const float*)d_in[11];
  const float* fc2_b = (const float*)d_in[12];
  const float* ln_g  = (const float*)d_in[13];
  const float* ln_b  = (const float*)d_in[14];
  float* out = (float*)d_out;

  lstm_fused<<<NBLK, 512, 0, stream>>>(x, w_ih1, w_hh1, b_ih1, b_hh1,
                                       w_ih2, w_hh2, b_ih2, b_hh2,
                                       fc1_w, fc1_b, fc2_w, fc2_b,
                                       ln_g, ln_b, out);
}

// Round 5
// 615.982 us; speedup vs baseline: 1.9349x; 1.2522x over previous
//
#include <hip/hip_runtime.h>
#include <cstdint>
#include <cstddef>

#define T_STEPS 1024
#define NBLK    256   // 512 batch / 2 per block

typedef __attribute__((ext_vector_type(8))) _Float16 half8;
typedef __attribute__((ext_vector_type(4))) float    f32x4;

static __device__ __forceinline__ float sigm(float x) {
  return __builtin_amdgcn_rcpf(1.0f + __expf(-x));
}
static __device__ __forceinline__ float tanh_(float x) {
  return 1.0f - 2.0f * __builtin_amdgcn_rcpf(__expf(2.0f * x) + 1.0f);
}

static __device__ __forceinline__ half8 load8(const float* s) {
  float4 a = ((const float4*)s)[0];
  float4 b = ((const float4*)s)[1];
  half8 h;
  h[0] = (_Float16)a.x; h[1] = (_Float16)a.y; h[2] = (_Float16)a.z; h[3] = (_Float16)a.w;
  h[4] = (_Float16)b.x; h[5] = (_Float16)b.y; h[6] = (_Float16)b.z; h[7] = (_Float16)b.w;
  return h;
}
static __device__ __forceinline__ half8 zero8() {
  half8 h;
  #pragma unroll
  for (int j = 0; j < 8; ++j) h[j] = (_Float16)0.0f;
  return h;
}

// Grid 256 x 512 threads; block = batch rows {2b, 2b+1} (MFMA D rows 0,1).
// Waves 0-3: L1, waves 4-7: L2. Tile tt = GATE TYPE (i,f,g,o), wave wq = unit
// group: gate row r = tt*64 + wq*16 + col. So after the MFMA, lanes 0-15 hold
// all 4 gates of unit u = wq*16 + lane (batch = reg 0/1) -> activations run
// in-wave: batch1 moved to lanes 16-31 via __shfl, 32 lanes do act, write h
// (f16) straight to the state buffer. ONE __syncthreads per phase.
// State S=[x(32)|h1(64)|h2(64)] f16, double-buffered. L1 K=96 (3 ksteps, no
// zero tile); L2 K=128 (4). Accumulator chain split into 2 parallel pairs.
// MFMA layouts (m89/m120-verified): A[m=l&15][k=(l>>4)*8+j];
// B[k=(l>>4)*8+j][n=l&15]; D[row=(l>>4)*4+reg][col=l&15].
__global__ __launch_bounds__(512, 2) void lstm_fused(
    const float* __restrict__ x,
    const float* __restrict__ w_ih1, const float* __restrict__ w_hh1,
    const float* __restrict__ b_ih1, const float* __restrict__ b_hh1,
    const float* __restrict__ w_ih2, const float* __restrict__ w_hh2,
    const float* __restrict__ b_ih2, const float* __restrict__ b_hh2,
    const float* __restrict__ fc1_w, const float* __restrict__ fc1_b,
    const float* __restrict__ fc2_w, const float* __restrict__ fc2_b,
    const float* __restrict__ ln_g, const float* __restrict__ ln_b,
    float* __restrict__ out)
{
  __shared__ __align__(16) _Float16 S[2][2][160];   // [buf][batch][x|h1|h2]
  __shared__ __align__(16) float hfin[2][64];
  __shared__ __align__(16) float y1s[2][128];
  __shared__ __align__(16) float y2s[2][128];
  __shared__ float redmu[2], redrs[2];

  const int t   = threadIdx.x;
  const int b   = blockIdx.x;
  const int l   = t & 63;
  const int w   = t >> 6;       // wave 0..7
  const int ly  = w >> 2;       // 0=L1, 1=L2
  const int wq  = w & 3;        // unit group
  const int col = l & 15;
  const int q   = l >> 4;       // quad

  // ---- init state: h1=h2=0 in both buffers ----
  if (t < 256) {
    const int bf = t >> 7, m = (t >> 6) & 1, uu = t & 63;
    S[bf][m][32 + uu] = (_Float16)0.0f;
    S[bf][m][96 + uu] = (_Float16)0.0f;
  }
  // x prefetch lanes: lanes 32..63 of waves 0,1 (disjoint from act lanes 0..31)
  const bool isx = (w < 2) && (l >= 32);
  const int  xm  = w;            // batch row
  const int  xi  = l - 32;       // 0..31
  const float* xp = x + ((size_t)(2 * b + xm)) * (T_STEPS * 32) + xi;
  if (isx) S[1][xm][xi] = (_Float16)xp[0];   // x_0 into phase-0 read buffer

  // ---- stationary weights -> B fragments wb[tile=gate][kstep] ----
  half8 wb[4][4];
  {
    const int ko = q * 8;
    #pragma unroll
    for (int tt = 0; tt < 4; ++tt) {
      const int r = tt * 64 + wq * 16 + col;   // gate row
      if (ly == 0) {
        wb[tt][0] = load8(w_ih1 + r * 32 + ko);        // k 0..31   x
        wb[tt][1] = load8(w_hh1 + r * 64 + ko);        // k 32..63  h1 lo
        wb[tt][2] = load8(w_hh1 + r * 64 + 32 + ko);   // k 64..95  h1 hi
        wb[tt][3] = zero8();                           // unused (L1 = 3 ksteps)
      } else {
        wb[tt][0] = load8(w_ih2 + r * 64 + ko);        // h1 lo
        wb[tt][1] = load8(w_ih2 + r * 64 + 32 + ko);   // h1 hi
        wb[tt][2] = load8(w_hh2 + r * 64 + ko);        // h2 lo
        wb[tt][3] = load8(w_hh2 + r * 64 + 32 + ko);   // h2 hi
      }
    }
  }

  // ---- act-lane setup: lanes 0..31, unit u, batch = q ----
  const int u = wq * 16 + (l & 15);
  float bia[4];
  {
    const float* bi_ = ly ? b_ih2 : b_ih1;
    const float* bh_ = ly ? b_hh2 : b_hh1;
    #pragma unroll
    for (int k2 = 0; k2 < 4; ++k2) bia[k2] = bi_[k2 * 64 + u] + bh_[k2 * 64 + u];
  }
  const int hoff = ly ? 96 : 32;

  float xr = 0.0f;
  if (isx) xr = xp[32];   // x_1
  float c = 0.0f;         // cell state (lanes 0..31: batch q, unit u)
  __syncthreads();

  for (int p = 0; p <= T_STEPS; ++p) {
    const int rd = (p + 1) & 1;
    const int wr = p & 1;

    float xr2 = 0.0f;
    if (isx && p + 2 < T_STEPS) xr2 = xp[(size_t)(p + 2) * 32];

    // ---- A fragments (state broadcast) ----
    const char* ab = (const char*)(&S[rd][0][0]) + (l & 1) * 320 + ly * 64 + q * 16;
    half8 af[4];
    #pragma unroll
    for (int ks = 0; ks < 4; ++ks) af[ks] = *(const half8*)(ab + ks * 64);

    // ---- MFMA: 2 parallel accumulator pairs per gate tile ----
    float ga[4], gb[4];   // gate pre-act, batch 0 / batch 1 (valid lanes 0-15)
    #pragma unroll
    for (int tt = 0; tt < 4; ++tt) {
      f32x4 aA = __builtin_amdgcn_mfma_f32_16x16x32_f16(af[0], wb[tt][0], (f32x4){0.f,0.f,0.f,0.f}, 0, 0, 0);
      aA = __builtin_amdgcn_mfma_f32_16x16x32_f16(af[1], wb[tt][1], aA, 0, 0, 0);
      f32x4 aB = __builtin_amdgcn_mfma_f32_16x16x32_f16(af[2], wb[tt][2], (f32x4){0.f,0.f,0.f,0.f}, 0, 0, 0);
      if (ly == 1)
        aB = __builtin_amdgcn_mfma_f32_16x16x32_f16(af[3], wb[tt][3], aB, 0, 0, 0);
      ga[tt] = aA[0] + aB[0];
      gb[tt] = aA[1] + aB[1];
    }

    // spread batch 1 to lanes 16..31 (one shuffle per gate)
    float gv[4];
    #pragma unroll
    for (int tt = 0; tt < 4; ++tt) {
      const float m1 = __shfl(gb[tt], l & 15, 64);
      gv[tt] = (l < 16) ? ga[tt] : m1;
    }

    // ---- in-wave activations: lanes 0..31 ----
    if (l < 32 && (ly == 0 || p > 0)) {
      const float gi = sigm(gv[0] + bia[0]);
      const float gf = sigm(gv[1] + bia[1]);
      const float gg = tanh_(gv[2] + bia[2]);
      const float go = sigm(gv[3] + bia[3]);
      c = gf * c + gi * gg;
      const float hv = go * tanh_(c);
      S[wr][q][hoff + u] = (_Float16)hv;
      if (ly == 1 && p == T_STEPS) hfin[q][u] = hv;   // h2_{T-1}
    }
    if (isx && p + 1 < T_STEPS) S[wr][xm][xi] = (_Float16)xr;
    xr = xr2;
    __syncthreads();
  }

  // ---- head: y = LN(relu(hT@fc1^T+b1)@fc2^T+b2), 2 batch rows ----
  if (t < 256) {
    const int bi = t >> 7, j = t & 127;
    float a = fc1_b[j];
    const float4* w4 = (const float4*)(fc1_w + j * 64);
    const float4* h4 = (const float4*)hfin[bi];
    #pragma unroll
    for (int qq = 0; qq < 16; ++qq) {
      float4 wv = w4[qq]; float4 hv = h4[qq];
      a += wv.x * hv.x + wv.y * hv.y + wv.z * hv.z + wv.w * hv.w;
    }
    y1s[bi][j] = fmaxf(a, 0.0f);
  }
  __syncthreads();
  if (t < 256) {
    const int bi = t >> 7, j = t & 127;
    float a = fc2_b[j];
    const float4* w4 = (const float4*)(fc2_w + j * 128);
    const float4* y4 = (const float4*)y1s[bi];
    #pragma unroll
    for (int qq = 0; qq < 32; ++qq) {
      float4 wv = w4[qq]; float4 yv = y4[qq];
      a += wv.x * yv.x + wv.y * yv.y + wv.z * yv.z + wv.w * yv.w;
    }
    y2s[bi][j] = a;
  }
  __syncthreads();
  if (t < 128) {
    const int bi = t >> 6, jj = t & 63;
    float s  = y2s[bi][jj] + y2s[bi][64 + jj];
    float qs = y2s[bi][jj] * y2s[bi][jj] + y2s[bi][64 + jj] * y2s[bi][64 + jj];
    #pragma unroll
    for (int off = 32; off > 0; off >>= 1) {
      s  += __shfl_down(s, off, 64);
      qs += __shfl_down(qs, off, 64);
    }
    if (jj == 0) {
      const float mu  = s * (1.0f / 128.0f);
      const float var = qs * (1.0f / 128.0f) - mu * mu;
      redmu[bi] = mu;
      redrs[bi] = rsqrtf(var + 1e-5f);
    }
  }
  __syncthreads();
  if (t < 256) {
    const int bi = t >> 7, j = t & 127;
    out[(size_t)(2 * b + bi) * 128 + j] =
        (y2s[bi][j] - redmu[bi]) * redrs[bi] * ln_g[j] + ln_b[j];
  }
}

extern "C" void kernel_launch(void* const* d_in, const int* in_sizes, int n_in,
                              void* d_out, int out_size, void* d_ws, size_t ws_size,
                              hipStream_t stream) {
  const float* x     = (const float*)d_in[0];
  const float* w_ih1 = (const float*)d_in[1];
  const float* w_hh1 = (const float*)d_in[2];
  const float* b_ih1 = (const float*)d_in[3];
  const float* b_hh1 = (const float*)d_in[4];
  const float* w_ih2 = (const float*)d_in[5];
  const float* w_hh2 = (const float*)d_in[6];
  const float* b_ih2 = (const float*)d_in[7];
  const float* b_hh2 = (const float*)d_in[8];
  const float* fc1_w = (const float*)d_in[9];
  const float* fc1_b = (const float*)d_in[10];
  const float* fc2_w = (const float*)d_in[11];
  const float* fc2_b = (const float*)d_in[12];
  const float* ln_g  = (const float*)d_in[13];
  const float* ln_b  = (const float*)d_in[14];
  float* out = (float*)d_out;

  lstm_fused<<<NBLK, 512, 0, stream>>>(x, w_ih1, w_hh1, b_ih1, b_hh1,
                                       w_ih2, w_hh2, b_ih2, b_hh2,
                                       fc1_w, fc1_b, fc2_w, fc2_b,
                                       ln_g, ln_b, out);
}

// Round 6
// 585.521 us; speedup vs baseline: 2.0356x; 1.0520x over previous
//
#include <hip/hip_runtime.h>
#include <cstdint>
#include <cstddef>

#define T_STEPS 1024
#define NBLK    256   // 512 batch / 2 per block

typedef __attribute__((ext_vector_type(8))) _Float16 half8;
typedef __attribute__((ext_vector_type(4))) _Float16 half4;
typedef __attribute__((ext_vector_type(4))) float    f32x4;

static __device__ __forceinline__ float sigm(float x) {
  return __builtin_amdgcn_rcpf(1.0f + __expf(-x));
}
static __device__ __forceinline__ float tanh_(float x) {
  return 1.0f - 2.0f * __builtin_amdgcn_rcpf(__expf(2.0f * x) + 1.0f);
}

static __device__ __forceinline__ half8 load8(const float* s) {
  float4 a = ((const float4*)s)[0];
  float4 b = ((const float4*)s)[1];
  half8 h;
  h[0] = (_Float16)a.x; h[1] = (_Float16)a.y; h[2] = (_Float16)a.z; h[3] = (_Float16)a.w;
  h[4] = (_Float16)b.x; h[5] = (_Float16)b.y; h[6] = (_Float16)b.z; h[7] = (_Float16)b.w;
  return h;
}
static __device__ __forceinline__ half8 zero8() {
  half8 h;
  #pragma unroll
  for (int j = 0; j < 8; ++j) h[j] = (_Float16)0.0f;
  return h;
}

// Grid 256 x 512 threads; block = batch rows {2b, 2b+1}, placed at MFMA A-rows
// 0 and 4 so D reg0 holds batch0 in lanes 0-15 and batch1 in lanes 16-31 (no
// shuffle). Waves 0-3: L1, 4-7: L2; wave owns all 4 gate types of 16 units
// (tile tt = gate type, row = tt*64 + wq*16 + col) -> in-wave activations.
// MFMAs fully chained per tile (L1: 3, L2: 4 ksteps).
// x is bulk-prefetched: every 16 phases, lanes 32-63 of all waves load 16
// timesteps (float4, coalesced) into a double-buffered LDS x-cache; L1
// pre-reads its x-fragment and pre-issues the x-kstep MFMAs BEFORE the
// barrier (x is available >=16 phases early), shrinking the post-barrier
// MFMA burst and filling the act-tail window.
// h-state: hstate[buf][batch][h1(64)|h2(64)] f16, double-buffered.
// ONE __syncthreads per phase.
// MFMA layouts (m89/m120-verified): A[m=l&15][k=(l>>4)*8+j];
// B[k=(l>>4)*8+j][n=l&15]; D[row=(l>>4)*4+reg][col=l&15].
__global__ __launch_bounds__(512, 2) void lstm_fused(
    const float* __restrict__ x,
    const float* __restrict__ w_ih1, const float* __restrict__ w_hh1,
    const float* __restrict__ b_ih1, const float* __restrict__ b_hh1,
    const float* __restrict__ w_ih2, const float* __restrict__ w_hh2,
    const float* __restrict__ b_ih2, const float* __restrict__ b_hh2,
    const float* __restrict__ fc1_w, const float* __restrict__ fc1_b,
    const float* __restrict__ fc2_w, const float* __restrict__ fc2_b,
    const float* __restrict__ ln_g, const float* __restrict__ ln_b,
    float* __restrict__ out)
{
  __shared__ __align__(16) _Float16 hstate[2][2][128];   // [buf][batch][h1|h2]
  __shared__ __align__(16) _Float16 xbig[2][16][2][32];  // [buf][slot][batch][i]
  __shared__ __align__(16) float hfin[2][64];
  __shared__ __align__(16) float y1s[2][128];
  __shared__ __align__(16) float y2s[2][128];
  __shared__ float redmu[2], redrs[2];

  const int t   = threadIdx.x;
  const int b   = blockIdx.x;
  const int l   = t & 63;
  const int w   = t >> 6;       // wave 0..7
  const int ly  = w >> 2;       // 0=L1, 1=L2
  const int wq  = w & 3;        // unit group
  const int col = l & 15;
  const int q   = l >> 4;       // quad
  const int m   = l & 15;       // A row this lane feeds
  const int bm  = (m >> 2) & 1; // batch for A row: rows 0-3->b0, 4-7->b1, ...

  // ---- init: zero h-state (both buffers) ----
  if (t < 512) ((_Float16*)hstate)[t] = (_Float16)0.0f;
  // ---- init: preload x[0..16) into xbig buf0 ----
  if (t < 256) {
    const int b0 = t >> 7, r0 = t & 127, tr0 = r0 >> 3, ii0 = r0 & 7;
    const float4 v = *(const float4*)(x + ((size_t)(2 * b + b0) * T_STEPS + tr0) * 32 + ii0 * 4);
    half4 h; h[0] = (_Float16)v.x; h[1] = (_Float16)v.y; h[2] = (_Float16)v.z; h[3] = (_Float16)v.w;
    *(half4*)((char*)xbig + tr0 * 128 + b0 * 64 + ii0 * 8) = h;
  }

  // ---- stationary weights -> B fragments wb[tile=gate][kstep] ----
  half8 wb[4][4];
  {
    const int ko = q * 8;
    #pragma unroll
    for (int tt = 0; tt < 4; ++tt) {
      const int r = tt * 64 + wq * 16 + col;
      if (ly == 0) {
        wb[tt][0] = load8(w_ih1 + r * 32 + ko);        // x
        wb[tt][1] = load8(w_hh1 + r * 64 + ko);        // h1 lo
        wb[tt][2] = load8(w_hh1 + r * 64 + 32 + ko);   // h1 hi
        wb[tt][3] = zero8();
      } else {
        wb[tt][0] = load8(w_ih2 + r * 64 + ko);        // h1 lo
        wb[tt][1] = load8(w_ih2 + r * 64 + 32 + ko);   // h1 hi
        wb[tt][2] = load8(w_hh2 + r * 64 + ko);        // h2 lo
        wb[tt][3] = load8(w_hh2 + r * 64 + 32 + ko);   // h2 hi
      }
    }
  }

  // ---- act-lane setup (lanes 0-31): unit u, batch = l>>4 ----
  const int u = wq * 16 + col;
  float bia[4];
  {
    const float* bi_ = ly ? b_ih2 : b_ih1;
    const float* bh_ = ly ? b_hh2 : b_hh1;
    #pragma unroll
    for (int k2 = 0; k2 < 4; ++k2) bia[k2] = bi_[k2 * 64 + u] + bh_[k2 * 64 + u];
  }
  const int hoff = ly ? 64 : 0;
  const int abm  = l >> 4;       // act batch (lanes 0-31)

  // ---- bulk x-prefetch lane mapping (lanes 32-63, all waves) ----
  const bool isx = (l >= 32);
  const int g   = w * 32 + (l - 32);      // 0..255
  const int xbm = g >> 7, xr = g & 127, xtr = xr >> 3, xii = xr & 7;
  const float* xsrc = x + ((size_t)(2 * b + xbm) * T_STEPS) * 32 + xii * 4;

  // per-lane LDS bases
  const char* xbase  = (const char*)xbig + bm * 64 + q * 16;      // + buf*2048 + slot*128
  const char* hbase0 = (const char*)hstate + bm * 256 + q * 16;   // + rd*512 + ks*64

  __syncthreads();

  // ---- pre-issue phase-0 x-kstep MFMAs (L1) ----
  f32x4 accp[4];
  #pragma unroll
  for (int tt = 0; tt < 4; ++tt) accp[tt] = (f32x4){0.f, 0.f, 0.f, 0.f};
  if (ly == 0) {
    const half8 a0 = *(const half8*)(xbase);   // buf0, slot0 = x_0
    #pragma unroll
    for (int tt = 0; tt < 4; ++tt)
      accp[tt] = __builtin_amdgcn_mfma_f32_16x16x32_f16(a0, wb[tt][0], accp[tt], 0, 0, 0);
  }

  float c = 0.0f;

  for (int p = 0; p <= T_STEPS; ++p) {
    const int rd = (p + 1) & 1;
    const int wr = p & 1;

    // issue bulk x loads at phase start (drained with ~full-phase slack)
    const bool doldx = ((p & 15) == 0) && isx && (p + 16 + xtr < T_STEPS);
    float4 xv;
    if (doldx) xv = *(const float4*)(xsrc + (size_t)(p + 16 + xtr) * 32);

    // ---- h-fragments + chained MFMAs ----
    const char* hb = hbase0 + rd * 512;
    f32x4 acc[4];
    if (ly == 0) {
      const half8 a1 = *(const half8*)(hb);        // h1 lo
      const half8 a2 = *(const half8*)(hb + 64);   // h1 hi
      #pragma unroll
      for (int tt = 0; tt < 4; ++tt) {
        acc[tt] = __builtin_amdgcn_mfma_f32_16x16x32_f16(a1, wb[tt][1], accp[tt], 0, 0, 0);
        acc[tt] = __builtin_amdgcn_mfma_f32_16x16x32_f16(a2, wb[tt][2], acc[tt], 0, 0, 0);
      }
    } else {
      const half8 a0 = *(const half8*)(hb);
      const half8 a1 = *(const half8*)(hb + 64);
      const half8 a2 = *(const half8*)(hb + 128);
      const half8 a3 = *(const half8*)(hb + 192);
      #pragma unroll
      for (int tt = 0; tt < 4; ++tt) {
        f32x4 a = __builtin_amdgcn_mfma_f32_16x16x32_f16(a0, wb[tt][0], (f32x4){0.f,0.f,0.f,0.f}, 0, 0, 0);
        a = __builtin_amdgcn_mfma_f32_16x16x32_f16(a1, wb[tt][1], a, 0, 0, 0);
        a = __builtin_amdgcn_mfma_f32_16x16x32_f16(a2, wb[tt][2], a, 0, 0, 0);
        acc[tt] = __builtin_amdgcn_mfma_f32_16x16x32_f16(a3, wb[tt][3], a, 0, 0, 0);
      }
    }

    // ---- in-wave activations: lanes 0-31, reg0 only (batch = l>>4) ----
    if (l < 32 && (ly == 0 || p > 0)) {
      const float gi = sigm(acc[0][0] + bia[0]);
      const float gf = sigm(acc[1][0] + bia[1]);
      const float gg = tanh_(acc[2][0] + bia[2]);
      const float go = sigm(acc[3][0] + bia[3]);
      c = gf * c + gi * gg;
      const float hv = go * tanh_(c);
      hstate[wr][abm][hoff + u] = (_Float16)hv;
      if (ly == 1 && p == T_STEPS) hfin[abm][u] = hv;   // h2_{T-1}
    }

    // ---- pre-read next x-frag + pre-issue x-kstep MFMAs (L1) ----
    if (ly == 0 && p < T_STEPS) {
      const int s  = (p + 1) & 15;
      const int bb = ((p + 1) >> 4) & 1;
      const half8 a0n = *(const half8*)(xbase + bb * 2048 + s * 128);
      #pragma unroll
      for (int tt = 0; tt < 4; ++tt)
        accp[tt] = __builtin_amdgcn_mfma_f32_16x16x32_f16(a0n, wb[tt][0], (f32x4){0.f,0.f,0.f,0.f}, 0, 0, 0);
    }

    // ---- stage bulk x into the other x-buffer ----
    if (doldx) {
      const int bb2 = ((p >> 4) + 1) & 1;
      half4 h; h[0] = (_Float16)xv.x; h[1] = (_Float16)xv.y; h[2] = (_Float16)xv.z; h[3] = (_Float16)xv.w;
      *(half4*)((char*)xbig + bb2 * 2048 + xtr * 128 + xbm * 64 + xii * 8) = h;
    }
    __syncthreads();
  }

  // ---- head: y = LN(relu(hT@fc1^T+b1)@fc2^T+b2), 2 batch rows ----
  if (t < 256) {
    const int bi = t >> 7, j = t & 127;
    float a = fc1_b[j];
    const float4* w4 = (const float4*)(fc1_w + j * 64);
    const float4* h4 = (const float4*)hfin[bi];
    #pragma unroll
    for (int qq = 0; qq < 16; ++qq) {
      float4 wv = w4[qq]; float4 hv = h4[qq];
      a += wv.x * hv.x + wv.y * hv.y + wv.z * hv.z + wv.w * hv.w;
    }
    y1s[bi][j] = fmaxf(a, 0.0f);
  }
  __syncthreads();
  if (t < 256) {
    const int bi = t >> 7, j = t & 127;
    float a = fc2_b[j];
    const float4* w4 = (const float4*)(fc2_w + j * 128);
    const float4* y4 = (const float4*)y1s[bi];
    #pragma unroll
    for (int qq = 0; qq < 32; ++qq) {
      float4 wv = w4[qq]; float4 yv = y4[qq];
      a += wv.x * yv.x + wv.y * yv.y + wv.z * yv.z + wv.w * yv.w;
    }
    y2s[bi][j] = a;
  }
  __syncthreads();
  if (t < 128) {
    const int bi = t >> 6, jj = t & 63;
    float s  = y2s[bi][jj] + y2s[bi][64 + jj];
    float qs = y2s[bi][jj] * y2s[bi][jj] + y2s[bi][64 + jj] * y2s[bi][64 + jj];
    #pragma unroll
    for (int off = 32; off > 0; off >>= 1) {
      s  += __shfl_down(s, off, 64);
      qs += __shfl_down(qs, off, 64);
    }
    if (jj == 0) {
      const float mu  = s * (1.0f / 128.0f);
      const float var = qs * (1.0f / 128.0f) - mu * mu;
      redmu[bi] = mu;
      redrs[bi] = rsqrtf(var + 1e-5f);
    }
  }
  __syncthreads();
  if (t < 256) {
    const int bi = t >> 7, j = t & 127;
    out[(size_t)(2 * b + bi) * 128 + j] =
        (y2s[bi][j] - redmu[bi]) * redrs[bi] * ln_g[j] + ln_b[j];
  }
}

extern "C" void kernel_launch(void* const* d_in, const int* in_sizes, int n_in,
                              void* d_out, int out_size, void* d_ws, size_t ws_size,
                              hipStream_t stream) {
  const float* x     = (const float*)d_in[0];
  const float* w_ih1 = (const float*)d_in[1];
  const float* w_hh1 = (const float*)d_in[2];
  const float* b_ih1 = (const float*)d_in[3];
  const float* b_hh1 = (const float*)d_in[4];
  const float* w_ih2 = (const float*)d_in[5];
  const float* w_hh2 = (const float*)d_in[6];
  const float* b_ih2 = (const float*)d_in[7];
  const float* b_hh2 = (const float*)d_in[8];
  const float* fc1_w = (const float*)d_in[9];
  const float* fc1_b = (const float*)d_in[10];
  const float* fc2_w = (const float*)d_in[11];
  const float* fc2_b = (const float*)d_in[12];
  const float* ln_g  = (const float*)d_in[13];
  const float* ln_b  = (const float*)d_in[14];
  float* out = (float*)d_out;

  lstm_fused<<<NBLK, 512, 0, stream>>>(x, w_ih1, w_hh1, b_ih1, b_hh1,
                                       w_ih2, w_hh2, b_ih2, b_hh2,
                                       fc1_w, fc1_b, fc2_w, fc2_b,
                                       ln_g, ln_b, out);
}